// Round 5
// baseline (544.063 us; speedup 1.0000x reference)
//
#include <hip/hip_runtime.h>

typedef unsigned int uint;
typedef unsigned short ushort;

#define NTOK   8192      // B*S
#define DIN    1024
#define DOUT   1024
#define NJ     96        // 84 decision nodes (12 trees x 7) + 12 gates
#define LOT_H  (NJ * DOUT)

// ---------------------------------------------------------------------------
// Kernel A (VALU): one token per block. decisions+gate dots, sigmoid, softmax,
// leaf-path products -> routed[8192][96] f32.
// ---------------------------------------------------------------------------
__global__ __launch_bounds__(256) void k_routed_valu(
    const float* __restrict__ x,     // [8192][1024]
    const float* __restrict__ dw,    // [84][1024]
    const float* __restrict__ db,    // [84]
    const float* __restrict__ ntl,   // [84]
    const float* __restrict__ gw,    // [12][1024]
    const float* __restrict__ gb,    // [12]
    const int*   __restrict__ pi,    // [8][3]
    const float* __restrict__ pd,    // [8][3]
    float* __restrict__ routed)      // [8192][96]
{
    __shared__ float4 xs4[256];      // one token's x row (1024 f32)
    __shared__ float  decis[96];     // raw logits
    __shared__ float  sdec[96];

    const int tid = threadIdx.x;
    const int tok = blockIdx.x;

    xs4[tid] = *(const float4*)(x + (size_t)tok * DIN + tid * 4);
    __syncthreads();

    // 96 dots of length 1024, two threads per dot (halves), shfl-combined
    const int j = tid >> 1, p = tid & 1;
    if (j < NJ) {
        const float* wrow = (j < 84) ? (dw + (size_t)j * DIN)
                                     : (gw + (size_t)(j - 84) * DIN);
        const float4* w4 = (const float4*)(wrow + p * 512);
        const float4* xv = xs4 + p * 128;
        float acc = 0.0f;
#pragma unroll 8
        for (int c = 0; c < 128; ++c) {
            float4 wv = w4[c], vv = xv[c];
            acc += wv.x * vv.x + wv.y * vv.y + wv.z * vv.z + wv.w * vv.w;
        }
        acc += __shfl_xor(acc, 1);
        if (p == 0) decis[j] = acc;
    }
    __syncthreads();

    // sigmoid(decision / softplus-temp) for the 84 internal nodes
    if (tid < 84) {
        float z = ntl[tid] + 0.5413f;
        float sp = (z > 20.0f) ? z : log1pf(__expf(z));   // softplus
        float dv = (decis[tid] + db[tid]) / sp;
        sdec[tid] = 1.0f / (1.0f + __expf(-dv));
    }
    __syncthreads();

    // one thread per (tree, leaf): gate softmax + depth-3 path product
    if (tid < NJ) {
        const int t = tid >> 3, l = tid & 7;
        float g[12], gm = -1e30f;
#pragma unroll
        for (int tt = 0; tt < 12; ++tt) {
            g[tt] = decis[84 + tt] + gb[tt];
            gm = fmaxf(gm, g[tt]);
        }
        float gs = 0.0f;
#pragma unroll
        for (int tt = 0; tt < 12; ++tt) gs += __expf(g[tt] - gm);
        float wgt = __expf(g[t] - gm) / gs;

        float pb = wgt;
#pragma unroll
        for (int dd = 0; dd < 3; ++dd) {
            int   node = pi[l * 3 + dd];
            float dir  = pd[l * 3 + dd];
            float sv   = sdec[t * 7 + node];
            pb *= dir * sv + (1.0f - dir) * (1.0f - sv);
        }
        routed[(size_t)tok * NJ + tid] = pb;
    }
}

// ---------------------------------------------------------------------------
// Kernel B (VALU): out[h][tok][d] = sum_k routed[tok][k] * lo[h][k][d]
// OUTPUT IS FLOAT32 (the round-4 discovery).
// ---------------------------------------------------------------------------
__global__ __launch_bounds__(256) void k_out_valu(
    const float* __restrict__ routed,  // [8192][96]
    const float* __restrict__ lo,      // [3][96][1024]
    float* __restrict__ out)           // [3][8192][1024] f32
{
    const int d  = blockIdx.y * 256 + threadIdx.x;
    const int tb = blockIdx.x * 16;
    const int h  = blockIdx.z;

    const float* lop = lo + (size_t)h * LOT_H + d;
    const float* rp  = routed + (size_t)tb * NJ;

    float acc[16];
#pragma unroll
    for (int t = 0; t < 16; ++t) acc[t] = 0.0f;

#pragma unroll 4
    for (int k = 0; k < NJ; ++k) {
        float lv = lop[(size_t)k * DOUT];
#pragma unroll
        for (int t = 0; t < 16; ++t)
            acc[t] += rp[t * NJ + k] * lv;
    }
#pragma unroll
    for (int t = 0; t < 16; ++t)
        out[((size_t)h * NTOK + tb + t) * DOUT + d] = acc[t];
}

// ---------------------------------------------------------------------------
extern "C" void kernel_launch(void* const* d_in, const int* in_sizes, int n_in,
                              void* d_out, int out_size, void* d_ws, size_t ws_size,
                              hipStream_t stream) {
    const float* x   = (const float*)d_in[0];
    const float* dw  = (const float*)d_in[1];
    const float* db  = (const float*)d_in[2];
    const float* ntl = (const float*)d_in[3];
    const float* gw  = (const float*)d_in[4];
    const float* gb  = (const float*)d_in[5];
    const float* lo  = (const float*)d_in[6];
    const int*   pi  = (const int*)d_in[7];
    const float* pd  = (const float*)d_in[8];
    float* out = (float*)d_out;

    float* routed = (float*)d_ws;    // 8192*96*4 = 3 MB scratch

    k_routed_valu<<<dim3(NTOK), dim3(256), 0, stream>>>(
        x, dw, db, ntl, gw, gb, pi, pd, routed);
    k_out_valu<<<dim3(NTOK / 16, DOUT / 256, 3), dim3(256), 0, stream>>>(
        routed, lo, out);
}

// Round 6
// 166.280 us; speedup vs baseline: 3.2720x; 3.2720x over previous
//
#include <hip/hip_runtime.h>

typedef __attribute__((ext_vector_type(8))) short short8;
typedef __attribute__((ext_vector_type(4))) float floatx4;
typedef unsigned int uint;
typedef unsigned short ushort;
typedef __attribute__((ext_vector_type(4))) uint uintx4;

#define NTOK   8192
#define DIN    1024
#define DOUT   1024
#define NJ     96        // 84 decision nodes (12 trees x 7) + 12 gates
#define TOKPB  32        // tokens per block (k_routed) -> 256 blocks
#define XSTR   136       // LDS row stride (bf16 elems): rows 16B-aligned, 2-way max conflict
#define DSTR   97        // decis LDS row stride (f32)
#define SSTR   85        // sdec LDS row stride (f32)
#define LOT_H  (DOUT * NJ)

static __device__ inline ushort f2b(float f) {
    uint u = __builtin_bit_cast(uint, f);
    u = u + 0x7fffu + ((u >> 16) & 1u);   // RNE
    return (ushort)(u >> 16);
}
static __device__ inline uint pack2(float a, float b) {
    return (uint)f2b(a) | ((uint)f2b(b) << 16);
}

// ---------------------------------------------------------------------------
// k_prep: f32 -> bf16.  lo [3][96][1024] -> lot [3][1024][96] (transposed);
// dw[84][1024] ++ gw[12][1024] -> wcat[96][1024].
// ---------------------------------------------------------------------------
__global__ __launch_bounds__(256) void k_prep(const float* __restrict__ lo,
                                              const float* __restrict__ dw,
                                              const float* __restrict__ gw,
                                              ushort* __restrict__ lot,
                                              ushort* __restrict__ wcat) {
    int i = blockIdx.x * 256 + threadIdx.x;
    if (i < 3 * LOT_H) {
        int h = i / LOT_H;
        int rem = i - h * LOT_H;
        int k = rem >> 10;
        int d = rem & 1023;
        lot[h * LOT_H + d * NJ + k] = f2b(lo[i]);
    } else {
        int j = i - 3 * LOT_H;
        int r = j >> 10, c = j & 1023;
        float v = (r < 84) ? dw[r * DIN + c] : gw[(r - 84) * DIN + c];
        wcat[j] = f2b(v);
    }
}

// ---------------------------------------------------------------------------
// k_routed: decisions+gates GEMM (MFMA bf16) + routing epilogue
//   -> routed[8192][96] bf16.  32 tokens/block, 256 blocks.
// Wave partition: wm=wave&1 picks token half (16 rows), wn=wave>>1 picks
// 48-wide j half; 3 acc tiles of 16x16 per wave.
// ---------------------------------------------------------------------------
__global__ __launch_bounds__(256) void k_routed(
    const float* __restrict__ x,     // [8192][1024] f32
    const ushort* __restrict__ wcat, // [96][1024] bf16
    const float* __restrict__ db,    // [84]
    const float* __restrict__ ntl,   // [84]
    const float* __restrict__ gb,    // [12]
    const int*   __restrict__ pi,    // [8][3]
    const float* __restrict__ pd,    // [8][3]
    ushort* __restrict__ routed)     // [8192][96]
{
    __shared__ __attribute__((aligned(16))) char smem[34816];
    __shared__ float invt[84];
    __shared__ float biasf[96];
    __shared__ int   pis[24];
    __shared__ float pds[24];

    ushort* xl = (ushort*)smem;                 // [32][XSTR] bf16
    ushort* wl = (ushort*)(smem + TOKPB * XSTR * 2);   // [96][XSTR] bf16
    float*  decis = (float*)smem;               // [32][DSTR] f32 (reuse)
    float*  sdecs = (float*)(smem + TOKPB * DSTR * 4); // [32][SSTR] f32

    const int tid = threadIdx.x;
    const int tb  = blockIdx.x * TOKPB;

    if (tid < 84) {
        float z = ntl[tid] + 0.5413f;
        float sp = (z > 20.0f) ? z : log1pf(__expf(z));   // softplus
        invt[tid]  = 1.0f / sp;
        biasf[tid] = db[tid];
    } else if (tid < 96) {
        biasf[tid] = gb[tid - 84];
    } else if (tid < 120) {
        pis[tid - 96] = pi[tid - 96];
    } else if (tid < 144) {
        pds[tid - 120] = pd[tid - 120];
    }

    const int wave = tid >> 6, lane = tid & 63;
    const int lrow = lane & 15, quad = lane >> 4;
    const int wm = wave & 1, wn = wave >> 1;

    floatx4 acc[3];
#pragma unroll
    for (int nt = 0; nt < 3; ++nt) acc[nt] = (floatx4)(0.0f);

    for (int kc = 0; kc < 8; ++kc) {
        __syncthreads();
        // stage x tile: 32 rows x 128 f32 -> bf16 (1024 float4 / 256 thr = 4)
#pragma unroll
        for (int i = 0; i < 4; ++i) {
            int idx = tid + 256 * i;
            int r = idx >> 5, c = idx & 31;
            float4 v = *(const float4*)(x + (size_t)(tb + r) * DIN + kc * 128 + c * 4);
            uint2 p;
            p.x = pack2(v.x, v.y);
            p.y = pack2(v.z, v.w);
            *(uint2*)(xl + r * XSTR + c * 4) = p;
        }
        // stage w tile: 96 rows x 128 bf16 (1536 uint4 / 256 thr = 6)
#pragma unroll
        for (int i = 0; i < 6; ++i) {
            int idx = tid + 256 * i;
            int r = idx >> 4, c = idx & 15;
            uintx4 v = *(const uintx4*)(wcat + r * DIN + kc * 128 + c * 8);
            *(uintx4*)(wl + r * XSTR + c * 8) = v;
        }
        __syncthreads();

        short8 a[4];
#pragma unroll
        for (int kt = 0; kt < 4; ++kt)
            a[kt] = *(const short8*)(xl + (wm * 16 + lrow) * XSTR + kt * 32 + quad * 8);
#pragma unroll
        for (int nt = 0; nt < 3; ++nt) {
#pragma unroll
            for (int kt = 0; kt < 4; ++kt) {
                short8 b = *(const short8*)(wl + (wn * 48 + nt * 16 + lrow) * XSTR + kt * 32 + quad * 8);
                acc[nt] = __builtin_amdgcn_mfma_f32_16x16x32_bf16(a[kt], b, acc[nt], 0, 0, 0);
            }
        }
    }

    __syncthreads();
    // C/D: col = lane&15 (j within 16-tile), row = quad*4+reg (token)
#pragma unroll
    for (int nt = 0; nt < 3; ++nt)
#pragma unroll
        for (int r = 0; r < 4; ++r)
            decis[(wm * 16 + quad * 4 + r) * DSTR + wn * 48 + nt * 16 + lrow] = acc[nt][r];
    __syncthreads();

    // stage 1: sigmoid over 32 tokens x 84 nodes = 2688
#pragma unroll
    for (int i = 0; i < 11; ++i) {
        int idx = tid + 256 * i;
        if (idx < TOKPB * 84) {
            int tk = idx / 84, nd = idx - tk * 84;
            float dv = (decis[tk * DSTR + nd] + biasf[nd]) * invt[nd];
            sdecs[tk * SSTR + nd] = 1.0f / (1.0f + __expf(-dv));
        }
    }
    __syncthreads();

    // stage 2: 256 threads = 32 tokens x 8 leaves
    {
        const int tk = tid >> 3, l = tid & 7;
        float g[12], gm = -1e30f;
#pragma unroll
        for (int tt = 0; tt < 12; ++tt) {
            g[tt] = decis[tk * DSTR + 84 + tt] + biasf[84 + tt];
            gm = fmaxf(gm, g[tt]);
        }
        float gs = 0.0f;
#pragma unroll
        for (int tt = 0; tt < 12; ++tt) { g[tt] = __expf(g[tt] - gm); gs += g[tt]; }
        float ginv = 1.0f / gs;

        const int   n0 = pis[l * 3 + 0], n1 = pis[l * 3 + 1], n2 = pis[l * 3 + 2];
        const float d0 = pds[l * 3 + 0], d1 = pds[l * 3 + 1], d2 = pds[l * 3 + 2];
        const float* sd = sdecs + tk * SSTR;
        ushort* dst = routed + (size_t)(tb + tk) * NJ + l;
#pragma unroll
        for (int t = 0; t < 12; ++t) {
            float s0 = sd[t * 7 + n0], s1 = sd[t * 7 + n1], s2 = sd[t * 7 + n2];
            float pb = g[t] * ginv
                     * (d0 * s0 + (1.0f - d0) * (1.0f - s0))
                     * (d1 * s1 + (1.0f - d1) * (1.0f - s1))
                     * (d2 * s2 + (1.0f - d2) * (1.0f - s2));
            dst[t * 8] = f2b(pb);
        }
    }
}

// ---------------------------------------------------------------------------
// k_out: out[h][tok][d] = sum_k routed[tok][k] * lot[h][d][k]  (MFMA, K=96)
// OUTPUT f32. grid: (128 token tiles, 16 d tiles, 3 heads).
// ---------------------------------------------------------------------------
__global__ __launch_bounds__(256) void k_out(
    const ushort* __restrict__ routed,  // [8192][96] bf16
    const ushort* __restrict__ lot,     // [3][1024][96] bf16
    float* __restrict__ out)            // [3][8192][1024] f32
{
    const int tb = blockIdx.x * 64;
    const int d0 = blockIdx.y * 64;
    const int h  = blockIdx.z;
    const int wave = threadIdx.x >> 6, lane = threadIdx.x & 63;
    const int lrow = lane & 15, quad = lane >> 4;

    const ushort* ap = routed + (size_t)(tb + wave * 16 + lrow) * NJ + quad * 8;
    short8 a[3];
#pragma unroll
    for (int kk = 0; kk < 3; ++kk) a[kk] = *(const short8*)(ap + kk * 32);

    const ushort* bp = lot + (size_t)h * LOT_H + (size_t)(d0 + lrow) * NJ + quad * 8;
    floatx4 acc[4];
#pragma unroll
    for (int nt = 0; nt < 4; ++nt) {
        acc[nt] = (floatx4)(0.0f);
#pragma unroll
        for (int kk = 0; kk < 3; ++kk) {
            short8 b = *(const short8*)(bp + nt * 16 * NJ + kk * 32);
            acc[nt] = __builtin_amdgcn_mfma_f32_16x16x32_bf16(a[kk], b, acc[nt], 0, 0, 0);
        }
    }
#pragma unroll
    for (int nt = 0; nt < 4; ++nt) {
        int d = d0 + nt * 16 + lrow;
#pragma unroll
        for (int r = 0; r < 4; ++r) {
            int tok = tb + wave * 16 + quad * 4 + r;
            out[((size_t)h * NTOK + tok) * DOUT + d] = acc[nt][r];
        }
    }
}

// ---------------------------------------------------------------------------
extern "C" void kernel_launch(void* const* d_in, const int* in_sizes, int n_in,
                              void* d_out, int out_size, void* d_ws, size_t ws_size,
                              hipStream_t stream) {
    const float* x   = (const float*)d_in[0];
    const float* dw  = (const float*)d_in[1];
    const float* db  = (const float*)d_in[2];
    const float* ntl = (const float*)d_in[3];
    const float* gw  = (const float*)d_in[4];
    const float* gb  = (const float*)d_in[5];
    const float* lo  = (const float*)d_in[6];
    const int*   pi  = (const int*)d_in[7];
    const float* pd  = (const float*)d_in[8];
    float* out = (float*)d_out;

    ushort* routed = (ushort*)d_ws;                    // 8192*96*2  = 1.57 MB
    ushort* lot    = routed + (size_t)NTOK * NJ;       // 3*98304*2  = 0.59 MB
    ushort* wcat   = lot + (size_t)3 * LOT_H;          // 96*1024*2  = 0.20 MB

    k_prep<<<dim3((3 * LOT_H + NJ * DIN) / 256), dim3(256), 0, stream>>>(lo, dw, gw, lot, wcat);
    k_routed<<<dim3(NTOK / TOKPB), dim3(256), 0, stream>>>(x, wcat, db, ntl, gb, pi, pd, routed);
    k_out<<<dim3(NTOK / 64, DOUT / 64, 3), dim3(256), 0, stream>>>(routed, lot, out);
}